// Round 5
// baseline (216.322 us; speedup 1.0000x reference)
//
#include <hip/hip_runtime.h>
#include <math.h>

#define EPSF 1e-5f

typedef __attribute__((ext_vector_type(8))) __bf16 bf16x8;
typedef __attribute__((ext_vector_type(4))) float f32x4;

__device__ __forceinline__ unsigned short f2bf(float f) {
  unsigned int u = __float_as_uint(f);
  u += 0x7FFFu + ((u >> 16) & 1u);
  return (unsigned short)(u >> 16);
}

__device__ __forceinline__ void async_load16(const void* g, void* l) {
  __builtin_amdgcn_global_load_lds(
      (const __attribute__((address_space(1))) void*)g,
      (__attribute__((address_space(3))) void*)l, 16, 0, 0);
}

// ---- fused: LN1+dt (blocks 0..2047) | weight transpose fp32->bf16 (2048..4095)
__global__ __launch_bounds__(256) void k_pre(
    const float* __restrict__ x, const float* __restrict__ g, const float* __restrict__ bta,
    const float* __restrict__ w_dt, const float* __restrict__ b_dt,
    const float* __restrict__ log_A, float* __restrict__ xn, float* __restrict__ log_a,
    const float* __restrict__ W1, unsigned short* __restrict__ W1t,
    const float* __restrict__ W2, unsigned short* __restrict__ W2t) {
  __shared__ float smem[64 * 65];
  int tid = threadIdx.x;
  if (blockIdx.x < 2048) {
    int bs = blockIdx.x;
    int t = tid;
    float4 v = ((const float4*)(x + (size_t)bs * 1024))[t];
    float s = v.x + v.y + v.z + v.w;
    float ss = v.x * v.x + v.y * v.y + v.z * v.z + v.w * v.w;
    #pragma unroll
    for (int o = 1; o < 64; o <<= 1) { s += __shfl_xor(s, o); ss += __shfl_xor(ss, o); }
    float* red = smem;
    int w = t >> 6;
    if ((t & 63) == 0) { red[w] = s; red[4 + w] = ss; }
    __syncthreads();
    float S = red[0] + red[1] + red[2] + red[3];
    float SS = red[4] + red[5] + red[6] + red[7];
    float m = S * (1.0f / 1024.0f);
    float var = SS * (1.0f / 1024.0f) - m * m;
    float inv = rsqrtf(var + EPSF);
    float4 gv = ((const float4*)g)[t];
    float4 bv = ((const float4*)bta)[t];
    float4 o;
    o.x = (v.x - m) * inv * gv.x + bv.x;
    o.y = (v.y - m) * inv * gv.y + bv.y;
    o.z = (v.z - m) * inv * gv.z + bv.z;
    o.w = (v.w - m) * inv * gv.w + bv.w;
    ((float4*)(xn + (size_t)bs * 1024))[t] = o;
    float4 wv = ((const float4*)w_dt)[t & 7];
    float part = o.x * wv.x + o.y * wv.y + o.z * wv.z + o.w * wv.w;
    part += __shfl_xor(part, 1);
    part += __shfl_xor(part, 2);
    part += __shfl_xor(part, 4);
    if ((t & 7) == 0) {
      int r = t >> 3;
      float z = part + b_dt[0];
      float sp = (z > 20.0f) ? z : log1pf(expf(z));
      log_a[(size_t)bs * 32 + r] = sp * (-expf(log_A[r]));
    }
  } else {
    int bid = blockIdx.x - 2048;
    const float* src; unsigned short* dst; int R, C, r0, c0;
    if (bid < 1024) { src = W1; dst = W1t; R = 1024; C = 4096;
                      c0 = (bid & 63) * 64; r0 = (bid >> 6) * 64; }
    else { bid -= 1024; src = W2; dst = W2t; R = 4096; C = 1024;
           c0 = (bid & 15) * 64; r0 = (bid >> 4) * 64; }
    #pragma unroll
    for (int q = 0; q < 4; ++q) {
      int lin = q * 256 + tid;
      int r = lin >> 4, cq = lin & 15;
      float4 v = *(const float4*)(src + (size_t)(r0 + r) * C + c0 + cq * 4);
      smem[r * 65 + cq * 4 + 0] = v.x; smem[r * 65 + cq * 4 + 1] = v.y;
      smem[r * 65 + cq * 4 + 2] = v.z; smem[r * 65 + cq * 4 + 3] = v.w;
    }
    __syncthreads();
    #pragma unroll
    for (int q = 0; q < 4; ++q) {
      int lin = q * 256 + tid;
      int c = lin >> 4, rq = lin & 15;
      ushort4 o;
      o.x = f2bf(smem[(rq * 4 + 0) * 65 + c]);
      o.y = f2bf(smem[(rq * 4 + 1) * 65 + c]);
      o.z = f2bf(smem[(rq * 4 + 2) * 65 + c]);
      o.w = f2bf(smem[(rq * 4 + 3) * 65 + c]);
      *(ushort4*)(dst + (size_t)(c0 + c) * R + r0 + rq * 4) = o;
    }
  }
}

// ---- chunked scan, float4 over c. grid (b,r,ch)=512; 256 thr = 32 sub x 8 cg
template <int PASS>
__global__ __launch_bounds__(256) void k_scan_pass(
    const float* __restrict__ xn, const float* __restrict__ x,
    const float* __restrict__ loga, float4* __restrict__ E, float* __restrict__ P,
    float* __restrict__ ssm) {
  int bx = blockIdx.x;
  int b = bx >> 8, r = (bx >> 3) & 31, ch = bx & 7;
  int tid = threadIdx.x, cg = tid & 7, sub = tid >> 3;
  __shared__ float dec[128];
  __shared__ float4 sE[32][8];
  __shared__ float sP[32];
  if (tid < 128)
    dec[tid] = expf(loga[(size_t)(b * 1024 + ch * 128 + tid) * 32 + r]);
  __syncthreads();
  int t0 = ch * 128 + sub * 4;
  size_t base = ((size_t)(b * 1024 + t0) * 1024 + r * 32 + cg * 4) >> 2;
  const float4* xn4 = (const float4*)xn;
  float4 xv[4];
  #pragma unroll
  for (int i = 0; i < 4; ++i) xv[i] = xn4[base + (size_t)i * 256];
  float4 S = {0.f, 0.f, 0.f, 0.f};
  float Pl = 1.0f;
  #pragma unroll
  for (int i = 0; i < 4; ++i) {
    float d = dec[sub * 4 + i];
    S.x = d * S.x + xv[i].x; S.y = d * S.y + xv[i].y;
    S.z = d * S.z + xv[i].z; S.w = d * S.w + xv[i].w;
    Pl *= d;
  }
  sE[sub][cg] = S;
  if (cg == 0) sP[sub] = Pl;
  __syncthreads();
  if (PASS == 0) {
    if (tid < 8) {
      float4 Et = {0.f, 0.f, 0.f, 0.f};
      float PP = 1.0f;
      #pragma unroll
      for (int h = 0; h < 32; ++h) {
        float p = sP[h]; float4 e = sE[h][tid];
        Et.x = p * Et.x + e.x; Et.y = p * Et.y + e.y;
        Et.z = p * Et.z + e.z; Et.w = p * Et.w + e.w;
        PP *= p;
      }
      E[((size_t)(b * 32 + r) * 8 + ch) * 8 + tid] = Et;
      if (tid == 0) P[(b * 32 + r) * 8 + ch] = PP;
    }
  } else {
    float4 Sin = {0.f, 0.f, 0.f, 0.f};
    const float4* Eb = E + (size_t)(b * 32 + r) * 64 + cg;
    const float* Pb = P + (size_t)(b * 32 + r) * 8;
    for (int h = 0; h < ch; ++h) {
      float p = Pb[h]; float4 e = Eb[h * 8];
      Sin.x = p * Sin.x + e.x; Sin.y = p * Sin.y + e.y;
      Sin.z = p * Sin.z + e.z; Sin.w = p * Sin.w + e.w;
    }
    for (int h = 0; h < sub; ++h) {
      float p = sP[h]; float4 e = sE[h][cg];
      Sin.x = p * Sin.x + e.x; Sin.y = p * Sin.y + e.y;
      Sin.z = p * Sin.z + e.z; Sin.w = p * Sin.w + e.w;
    }
    const float4* x4 = (const float4*)x;
    float4* ssm4 = (float4*)ssm;
    #pragma unroll
    for (int i = 0; i < 4; ++i) {
      float d = dec[sub * 4 + i];
      Sin.x = d * Sin.x + xv[i].x; Sin.y = d * Sin.y + xv[i].y;
      Sin.z = d * Sin.z + xv[i].z; Sin.w = d * Sin.w + xv[i].w;
      float4 rx = x4[base + (size_t)i * 256];
      float4 o;
      o.x = Sin.x + rx.x; o.y = Sin.y + rx.y;
      o.z = Sin.z + rx.z; o.w = Sin.w + rx.w;
      ssm4[base + (size_t)i * 256] = o;
    }
  }
}

// ---- LN2 -> fn bf16 (blocks 0..2047) | out init = ssm + bb2 (2048..4095) ----
__global__ __launch_bounds__(256) void k_ln2_init(
    const float* __restrict__ ssm, const float* __restrict__ g, const float* __restrict__ bta,
    unsigned short* __restrict__ fn, const float* __restrict__ bb2,
    float* __restrict__ out) {
  int tid = threadIdx.x;
  if (blockIdx.x >= 2048) {
    int i = (blockIdx.x - 2048) * 256 + tid;   // float4 idx over 2048x1024
    float4 v = ((const float4*)ssm)[i];
    float4 bb = ((const float4*)bb2)[i & 255];
    float4 o;
    o.x = v.x + bb.x; o.y = v.y + bb.y; o.z = v.z + bb.z; o.w = v.w + bb.w;
    ((float4*)out)[i] = o;
    return;
  }
  int bs = blockIdx.x;
  int t = tid;
  float4 v = ((const float4*)(ssm + (size_t)bs * 1024))[t];
  float s = v.x + v.y + v.z + v.w;
  float ss = v.x * v.x + v.y * v.y + v.z * v.z + v.w * v.w;
  #pragma unroll
  for (int o = 1; o < 64; o <<= 1) { s += __shfl_xor(s, o); ss += __shfl_xor(ss, o); }
  __shared__ float red[8];
  int w = t >> 6;
  if ((t & 63) == 0) { red[w] = s; red[4 + w] = ss; }
  __syncthreads();
  float S = red[0] + red[1] + red[2] + red[3];
  float SS = red[4] + red[5] + red[6] + red[7];
  float m = S * (1.0f / 1024.0f);
  float var = SS * (1.0f / 1024.0f) - m * m;
  float inv = rsqrtf(var + EPSF);
  float4 gv = ((const float4*)g)[t];
  float4 bv = ((const float4*)bta)[t];
  ushort4 o;
  o.x = f2bf((v.x - m) * inv * gv.x + bv.x);
  o.y = f2bf((v.y - m) * inv * gv.y + bv.y);
  o.z = f2bf((v.z - m) * inv * gv.z + bv.z);
  o.w = f2bf((v.w - m) * inv * gv.w + bv.w);
  ((ushort4*)(fn + (size_t)bs * 1024))[t] = o;
}

// ---- m97-core bf16 MFMA GEMM, 512 threads (8 waves of 64x64), BK=32,
// single-buffer LDS + __syncthreads, async global_load_lds width-16.
// EPI 0: C(bf16) = gelu(acc + bias[n]).  EPI 1: atomicAdd fp32 into C.
template <int BM, int BN, int EPI>
__global__ __launch_bounds__(512) void k_gemm(
    const unsigned short* __restrict__ A, const unsigned short* __restrict__ Bt,
    const float* __restrict__ bias, void* __restrict__ C,
    int M, int N, int K, int KS) {
  constexpr int AR = BM / 128;   // A staging rounds per thread (512 thr, 16B each)
  constexpr int BR = BN / 128;
  __shared__ __align__(16) unsigned short sA[BM * 32];
  __shared__ __align__(16) unsigned short sB[BN * 32];
  int m0 = blockIdx.y * BM, n0 = blockIdx.x * BN;
  int kLen = K / KS, kOff = blockIdx.z * kLen;
  int tid = threadIdx.x;
  int wave = tid >> 6, lane = tid & 63;
  int wr, wc;
  if (BM == 256) { wr = wave >> 1; wc = wave & 1; }
  else           { wr = wave & 1;  wc = wave >> 1; }
  int l15 = lane & 15, quad = lane >> 4;

  const unsigned short* gA[AR]; unsigned short* lA[AR];
  const unsigned short* gB[BR]; unsigned short* lB[BR];
  #pragma unroll
  for (int a = 0; a < AR; ++a) {
    int q = tid + a * 512;
    gA[a] = A + (size_t)(m0 + (q >> 2)) * K + kOff + (q & 3) * 8;
    lA[a] = sA + (size_t)(q & ~63) * 8;
  }
  #pragma unroll
  for (int b = 0; b < BR; ++b) {
    int q = tid + b * 512;
    gB[b] = Bt + (size_t)(n0 + (q >> 2)) * K + kOff + (q & 3) * 8;
    lB[b] = sB + (size_t)(q & ~63) * 8;
  }

  f32x4 zero = {0.0f, 0.0f, 0.0f, 0.0f};
  f32x4 acc[4][4];
  #pragma unroll
  for (int i = 0; i < 4; ++i)
    #pragma unroll
    for (int j = 0; j < 4; ++j) acc[i][j] = zero;

  const unsigned short* pa = sA + (wr * 64 + l15) * 32 + quad * 8;
  const unsigned short* pb = sB + (wc * 64 + l15) * 32 + quad * 8;

  for (int k0 = 0; k0 < kLen; k0 += 32) {
    #pragma unroll
    for (int a = 0; a < AR; ++a) { async_load16(gA[a], lA[a]); gA[a] += 32; }
    #pragma unroll
    for (int b = 0; b < BR; ++b) { async_load16(gB[b], lB[b]); gB[b] += 32; }
    __syncthreads();
    bf16x8 af[4], bfr[4];
    #pragma unroll
    for (int i = 0; i < 4; ++i) af[i] = *(const bf16x8*)(pa + i * 512);
    #pragma unroll
    for (int j = 0; j < 4; ++j) bfr[j] = *(const bf16x8*)(pb + j * 512);
    #pragma unroll
    for (int i = 0; i < 4; ++i)
      #pragma unroll
      for (int j = 0; j < 4; ++j)
        acc[i][j] = __builtin_amdgcn_mfma_f32_16x16x32_bf16(af[i], bfr[j], acc[i][j], 0, 0, 0);
    __syncthreads();
  }

  if (EPI == 0) {
    unsigned short* Cb = (unsigned short*)C;
    #pragma unroll
    for (int i = 0; i < 4; ++i)
      #pragma unroll
      for (int j = 0; j < 4; ++j) {
        int col = n0 + wc * 64 + j * 16 + l15;
        float bval = bias[col];
        #pragma unroll
        for (int v = 0; v < 4; ++v) {
          int row = m0 + wr * 64 + i * 16 + quad * 4 + v;
          float val = acc[i][j][v] + bval;
          val = 0.5f * val * (1.0f + erff(val * 0.70710678118654752f));
          Cb[(size_t)row * N + col] = f2bf(val);
        }
      }
  } else {
    float* O = (float*)C;
    #pragma unroll
    for (int i = 0; i < 4; ++i)
      #pragma unroll
      for (int j = 0; j < 4; ++j) {
        int col = n0 + wc * 64 + j * 16 + l15;
        #pragma unroll
        for (int v = 0; v < 4; ++v) {
          int row = m0 + wr * 64 + i * 16 + quad * 4 + v;
          atomicAdd(&O[(size_t)row * N + col], acc[i][j][v]);
        }
      }
  }
}

extern "C" void kernel_launch(void* const* d_in, const int* in_sizes, int n_in,
                              void* d_out, int out_size, void* d_ws, size_t ws_size,
                              hipStream_t stream) {
  const float* x     = (const float*)d_in[0];
  const float* log_A = (const float*)d_in[1];
  const float* w_dt  = (const float*)d_in[2];
  const float* b_dt  = (const float*)d_in[3];
  const float* g_ssm = (const float*)d_in[4];
  const float* b_ssm = (const float*)d_in[5];
  const float* g_ffn = (const float*)d_in[6];
  const float* b_ffn = (const float*)d_in[7];
  const float* W1    = (const float*)d_in[8];
  const float* bb1   = (const float*)d_in[9];
  const float* W2    = (const float*)d_in[10];
  const float* bb2   = (const float*)d_in[11];
  float* out = (float*)d_out;

  const size_t MB = 1u << 20;
  char* ws = (char*)d_ws;
  float* xn            = (float*)(ws);                       // 0-8
  unsigned short* W1t  = (unsigned short*)(ws + 8 * MB);     // 8-16
  float* loga          = (float*)(ws + 16 * MB);
  float4* Ebuf         = (float4*)(ws + 16 * MB + 262144);
  float* Pbuf          = (float*)(ws + 16 * MB + 393216);
  unsigned short* fn   = (unsigned short*)(ws + 17 * MB);    // 17-21
  unsigned short* W2t  = (unsigned short*)(ws + 21 * MB);    // 21-29
  float* ssm           = (float*)(ws + 29 * MB);             // 29-37
  unsigned short* hbf  = (unsigned short*)(ws + 37 * MB);    // 37-53

  k_pre<<<4096, 256, 0, stream>>>(x, g_ssm, b_ssm, w_dt, b_dt, log_A, xn, loga,
                                  W1, W1t, W2, W2t);
  k_scan_pass<0><<<512, 256, 0, stream>>>(xn, x, loga, Ebuf, Pbuf, ssm);
  k_scan_pass<1><<<512, 256, 0, stream>>>(xn, x, loga, Ebuf, Pbuf, ssm);
  k_ln2_init<<<4096, 256, 0, stream>>>(ssm, g_ffn, b_ffn, fn, bb2, out);
  // GEMM1: 256x128 tiles, grid 32x8 = 256 blocks
  k_gemm<256, 128, 0><<<dim3(32, 8, 1), 512, 0, stream>>>(
      fn, W1t, bb1, (void*)hbf, 2048, 4096, 1024, 1);
  // GEMM2: 128x256 tiles, split-K=4, atomic accumulate into out
  k_gemm<128, 256, 1><<<dim3(4, 16, 4), 512, 0, stream>>>(
      hbf, W2t, nullptr, (void*)out, 2048, 1024, 4096, 4);
}